// Round 1
// baseline (1078.769 us; speedup 1.0000x reference)
//
#include <hip/hip_runtime.h>

#define DD 64      // feature dim
#define MM 128     // time points per path
#define PP 127     // increments per path

// One wave (64 threads) per (gram, a, b) pair.
// gram 0: K(X_a, X_b), gram 1: K(Y_a, Y_b), gram 2: K(X_a, Y_b).
// For grams 0/1 only a<=b is computed (kernel is symmetric).
//
// Goursat recurrence K[p+1][q+1] = K[p+1][q] + K[p][q+1] - K[p][q] + inc*K[p][q]
// restructured as per-row prefix sum:
//   c[q]     = K[p][q+1] - K[p][q] + inc[p][q]*K[p][q]
//   K[p+1][j] = K[p+1][base] + inclusive_scan(c)[j-1]
// with inc[p][q] = s[p+1] - s[p],  s[p] = dot(U_row[p], dV_row[q]).
// Lane l owns column q = 64*s + l; dV row lives in 64 VGPRs; U rows are
// broadcast from a small double-buffered LDS chunk.
__global__ __launch_bounds__(64, 4) void sig_goursat_kernel(
        const float* __restrict__ X, const float* __restrict__ Y,
        float* __restrict__ Kout)
{
    const int bid = blockIdx.x;
    const int g   = bid >> 12;        // 0..2
    const int pid = bid & 4095;
    const int a   = pid >> 6;
    const int b   = pid & 63;
    if (g < 2 && a > b) return;       // symmetric grams: upper triangle only

    const float* __restrict__ U = (g == 1 ? Y : X) + (size_t)a * (MM * DD);
    const float* __restrict__ V = (g == 0 ? X : Y) + (size_t)b * (MM * DD);

    const int lane = threadIdx.x;

    __shared__ float bnd[MM + 1];                    // K[p][64], p = 0..127
    __shared__ __align__(16) float uch[2][8][DD];    // double-buffered U chunks

    if (lane == 0) bnd[0] = 1.0f;                    // K[0][64] = 1

    float result = 0.0f;

    for (int s = 0; s < 2; ++s) {
        const int q  = s * 64 + lane;                // cell column this lane owns
        const int qa = q > 126 ? 126 : q;            // clamp inactive lane (s=1,l=63)

        // ---- dV row into registers (reused for all 127 row-steps) ----
        float dv[DD];
        #pragma unroll
        for (int d = 0; d < DD; d += 4) {
            float4 v0 = *(const float4*)(V + (size_t)qa * DD + d);
            float4 v1 = *(const float4*)(V + (size_t)(qa + 1) * DD + d);
            dv[d + 0] = v1.x - v0.x;
            dv[d + 1] = v1.y - v0.y;
            dv[d + 2] = v1.z - v0.z;
            dv[d + 3] = v1.w - v0.w;
        }

        // per-lane dot of an LDS-resident U row (broadcast reads) with dv
        auto ldot = [&](const float* ur) -> float {
            float a0 = 0.f, a1 = 0.f, a2 = 0.f, a3 = 0.f;
            #pragma unroll
            for (int d = 0; d < DD; d += 4) {
                float4 u = *(const float4*)(ur + d);
                a0 = fmaf(u.x, dv[d + 0], a0);
                a1 = fmaf(u.y, dv[d + 1], a1);
                a2 = fmaf(u.z, dv[d + 2], a2);
                a3 = fmaf(u.w, dv[d + 3], a3);
            }
            return (a0 + a1) + (a2 + a3);
        };

        // ---- stage chunk 0 (U rows 0..7): 512 floats, 2 x float4 per lane ----
        {
            float4 t0 = *(const float4*)(U + lane * 4);
            float4 t1 = *(const float4*)(U + 256 + lane * 4);
            *(float4*)(&uch[0][0][0] + lane * 4) = t0;
            *(float4*)(&uch[0][0][0] + 256 + lane * 4) = t1;
        }
        __syncthreads();

        float s0 = ldot(&uch[0][0][0]);   // s[0] = dot(U[0], dv)
        float K  = 1.0f;                  // K[0][q+1] = 1

        for (int c = 0; c < 16; ++c) {    // 16 chunks x 8 U-rows = rows 0..127
            const int buf = c & 1;
            float4 t0, t1;
            if (c < 15) {                 // prefetch next chunk into regs
                const float* gsrc = U + (c + 1) * 512;
                t0 = *(const float4*)(gsrc + lane * 4);
                t1 = *(const float4*)(gsrc + 256 + lane * 4);
            }
            #pragma unroll
            for (int rr = 0; rr < 8; ++rr) {
                if (rr == 0 && c == 0) continue;     // U row 0 already consumed
                const int p = c * 8 + rr - 1;        // computes K row p+1
                float s1  = ldot(&uch[buf][rr][0]);
                float inc = s1 - s0;
                s0 = s1;
                float Kprev = __shfl_up(K, 1, 64);   // K[p][q]
                if (lane == 0) Kprev = (s == 0) ? 1.0f : bnd[p];
                float cv = (K - Kprev) + inc * Kprev;
                // inclusive scan of cv across the wave
                #pragma unroll
                for (int off = 1; off < 64; off <<= 1) {
                    float t = __shfl_up(cv, off, 64);
                    if (lane >= off) cv += t;
                }
                float base = (s == 0) ? 1.0f : bnd[p + 1];
                K = base + cv;                        // K[p+1][q+1]
                if (s == 0 && lane == 63) bnd[p + 1] = K;  // K[p+1][64]
            }
            if (c < 15) {
                float* ldst = &uch[buf ^ 1][0][0];
                *(float4*)(ldst + lane * 4) = t0;
                *(float4*)(ldst + 256 + lane * 4) = t1;
            }
            __syncthreads();
        }
        __syncthreads();   // bnd[] complete before strip 1 consumes it
        if (s == 1 && lane == 62) result = K;   // K[127][127]
    }

    if (lane == 62) Kout[(size_t)g * 4096 + pid] = result;
}

// Deterministic weighted reduction + the mean((X0-Y0)^2) term.
__global__ void sig_reduce_kernel(const float* __restrict__ X,
                                  const float* __restrict__ Y,
                                  const float* __restrict__ Kws,
                                  float* __restrict__ out)
{
    const int t = threadIdx.x;
    double accK = 0.0, acc2 = 0.0;
    for (int i = t; i < 4096; i += 256) {
        const int a = i >> 6, b = i & 63;
        if (a <= b) {
            const double w = (a == b) ? 1.0 : 2.0;
            accK += w * (double)Kws[i];           // XX
            accK += w * (double)Kws[4096 + i];    // YY
        }
        accK -= 2.0 * (double)Kws[8192 + i];      // XY
        // mean((X[:,0,:] - Y[:,0,:])^2): element (a, d=b)
        const float df = X[(size_t)a * (MM * DD) + b] - Y[(size_t)a * (MM * DD) + b];
        acc2 += (double)df * (double)df;
    }
    __shared__ double red[256];
    red[t] = accK / 4096.0 + acc2 / 4096.0;
    __syncthreads();
    for (int s = 128; s > 0; s >>= 1) {
        if (t < s) red[t] += red[t + s];
        __syncthreads();
    }
    if (t == 0) out[0] = (float)red[0];
}

extern "C" void kernel_launch(void* const* d_in, const int* in_sizes, int n_in,
                              void* d_out, int out_size, void* d_ws, size_t ws_size,
                              hipStream_t stream) {
    const float* X = (const float*)d_in[0];
    const float* Y = (const float*)d_in[1];
    float* Kws = (float*)d_ws;          // 3 * 4096 floats
    float* out = (float*)d_out;

    sig_goursat_kernel<<<dim3(3 * 4096), dim3(64), 0, stream>>>(X, Y, Kws);
    sig_reduce_kernel<<<dim3(1), dim3(256), 0, stream>>>(X, Y, Kws, out);
}

// Round 2
// 452.060 us; speedup vs baseline: 2.3863x; 2.3863x over previous
//
#include <hip/hip_runtime.h>

#define DD 64      // feature dim
#define MM 128     // time points per path
#define PP 127     // increments per path

#define FOR16(F) F(0) F(1) F(2) F(3) F(4) F(5) F(6) F(7) \
                 F(8) F(9) F(10) F(11) F(12) F(13) F(14) F(15)

// One wave (64 threads) per (gram, a, b) pair.
// gram 0: K(X_a, X_b), gram 1: K(Y_a, Y_b), gram 2: K(X_a, Y_b).
// Grams 0/1: only a<=b computed (kernel symmetric); reducer weights x2.
//
// Goursat recurrence K[p+1][q+1] = K[p+1][q] + K[p][q+1] - K[p][q] + inc*K[p][q]
// as a per-row prefix sum:
//   cv[q]      = K[p][q+1] - K[p][q] + inc[p][q]*K[p][q]
//   K[p+1][j]  = K[p+1][strip_base] + inclusive_scan(cv)
// with inc[p][q] = s[p+1] - s[p],  s[p] = dot(U_row[p], dV_row[q]).
// Lane l owns column q = 64*s + l. dV row lives in 16 NAMED float4 registers
// (no array -> no scratch demotion). U rows are read directly from global
// with wave-uniform addresses (one coalesced L1/L2-resident request each).
__global__ __launch_bounds__(64, 2) void sig_goursat_kernel(
        const float* __restrict__ X, const float* __restrict__ Y,
        float* __restrict__ Kout)
{
    const int bid = blockIdx.x;
    const int g   = bid >> 12;        // 0..2
    const int pid = bid & 4095;
    const int a   = pid >> 6;
    const int b   = pid & 63;
    if (g < 2 && a > b) return;       // symmetric grams: upper triangle only

    const float* __restrict__ U = (g == 1 ? Y : X) + (size_t)a * (MM * DD);
    const float* __restrict__ V = (g == 0 ? X : Y) + (size_t)b * (MM * DD);

    const int lane = threadIdx.x;

    __shared__ float bnd[MM];         // bnd[p] = K[p][64], p = 0..127
    if (lane == 0) bnd[0] = 1.0f;     // K[0][64] = 1

    float result = 0.0f;

    for (int s = 0; s < 2; ++s) {
        const int q  = s * 64 + lane;             // cell column this lane owns
        const int qa = q > 126 ? 126 : q;         // clamp inactive lane (s=1,l=63)

        // ---- dV row in 16 named float4 registers (64 VGPRs, reused 128x) ----
        const float* __restrict__ Vr0 = V + (size_t)qa * DD;
        const float* __restrict__ Vr1 = V + (size_t)(qa + 1) * DD;
#define DVDECL(i) float4 dv##i;
        FOR16(DVDECL)
#define DVLOAD(i) { float4 v0_ = *(const float4*)(Vr0 + 4*(i)); \
                    float4 v1_ = *(const float4*)(Vr1 + 4*(i)); \
                    dv##i.x = v1_.x - v0_.x; dv##i.y = v1_.y - v0_.y; \
                    dv##i.z = v1_.z - v0_.z; dv##i.w = v1_.w - v0_.w; }
        FOR16(DVLOAD)

#define DOTSTEP(i) { float4 u_ = *(const float4*)(ur_ + 4*(i)); \
                     acc0 = fmaf(u_.x, dv##i.x, acc0); \
                     acc1 = fmaf(u_.y, dv##i.y, acc1); \
                     acc2 = fmaf(u_.z, dv##i.z, acc2); \
                     acc3 = fmaf(u_.w, dv##i.w, acc3); }
#define DOT(rowptr, out) { const float* __restrict__ ur_ = (rowptr); \
                           float acc0 = 0.f, acc1 = 0.f, acc2 = 0.f, acc3 = 0.f; \
                           FOR16(DOTSTEP) \
                           out = (acc0 + acc1) + (acc2 + acc3); }

        float s0;
        DOT(U, s0)                    // s[0] = dot(U[0], dv)
        float K = 1.0f;               // K[0][q+1] = 1

        for (int p = 0; p < PP; ++p) {            // computes K row p+1
            float s1;
            DOT(U + (size_t)(p + 1) * DD, s1)
            const float inc = s1 - s0;
            s0 = s1;

            float Kprev = __shfl_up(K, 1, 64);    // K[p][q]
            if (lane == 0) Kprev = (s == 0) ? 1.0f : bnd[p];
            float cv = (K - Kprev) + inc * Kprev;

            // inclusive scan of cv across the wave (6 steps)
            #pragma unroll
            for (int off = 1; off < 64; off <<= 1) {
                float t = __shfl_up(cv, off, 64);
                if (lane >= off) cv += t;
            }

            const float base = (s == 0) ? 1.0f : bnd[p + 1];  // K[p+1][strip base]
            K = base + cv;                                     // K[p+1][q+1]
            if (s == 0 && lane == 63) bnd[p + 1] = K;          // K[p+1][64]
        }
        __syncthreads();   // strip 0's bnd[] complete before strip 1 reads it
        if (s == 1 && lane == 62) result = K;     // K[127][127]
    }

    if (lane == 62) Kout[(size_t)g * 4096 + pid] = result;
}

// Deterministic weighted reduction + the mean((X0-Y0)^2) term.
__global__ void sig_reduce_kernel(const float* __restrict__ X,
                                  const float* __restrict__ Y,
                                  const float* __restrict__ Kws,
                                  float* __restrict__ out)
{
    const int t = threadIdx.x;
    double accK = 0.0, acc2 = 0.0;
    for (int i = t; i < 4096; i += 256) {
        const int a = i >> 6, b = i & 63;
        if (a <= b) {
            const double w = (a == b) ? 1.0 : 2.0;
            accK += w * (double)Kws[i];           // XX
            accK += w * (double)Kws[4096 + i];    // YY
        }
        accK -= 2.0 * (double)Kws[8192 + i];      // XY
        // mean((X[:,0,:] - Y[:,0,:])^2): element (a, d=b)
        const float df = X[(size_t)a * (MM * DD) + b] - Y[(size_t)a * (MM * DD) + b];
        acc2 += (double)df * (double)df;
    }
    __shared__ double red[256];
    red[t] = accK / 4096.0 + acc2 / 4096.0;
    __syncthreads();
    for (int s = 128; s > 0; s >>= 1) {
        if (t < s) red[t] += red[t + s];
        __syncthreads();
    }
    if (t == 0) out[0] = (float)red[0];
}

extern "C" void kernel_launch(void* const* d_in, const int* in_sizes, int n_in,
                              void* d_out, int out_size, void* d_ws, size_t ws_size,
                              hipStream_t stream) {
    const float* X = (const float*)d_in[0];
    const float* Y = (const float*)d_in[1];
    float* Kws = (float*)d_ws;          // 3 * 4096 floats
    float* out = (float*)d_out;

    sig_goursat_kernel<<<dim3(3 * 4096), dim3(64), 0, stream>>>(X, Y, Kws);
    sig_reduce_kernel<<<dim3(1), dim3(256), 0, stream>>>(X, Y, Kws, out);
}

// Round 3
// 347.218 us; speedup vs baseline: 3.1069x; 1.3019x over previous
//
#include <hip/hip_runtime.h>
#include <math.h>

#define DD 64      // feature dim
#define MM 128     // time points per path
#define PP 127     // increments per path

#define FOR16(F) F(0) F(1) F(2) F(3) F(4) F(5) F(6) F(7) \
                 F(8) F(9) F(10) F(11) F(12) F(13) F(14) F(15)

// ---- wave64 inclusive add-scan via DPP (classic GCN sequence, ~12 VALU) ----
template<int CTRL, int RM, bool BC>
__device__ __forceinline__ float dpp_add(float x) {
    int t = __builtin_amdgcn_update_dpp(0, __float_as_int(x), CTRL, RM, 0xf, BC);
    return x + __int_as_float(t);
}
__device__ __forceinline__ float wave_incl_scan(float x) {
    x = dpp_add<0x111, 0xf, true >(x);   // row_shr:1
    x = dpp_add<0x112, 0xf, true >(x);   // row_shr:2
    x = dpp_add<0x114, 0xf, true >(x);   // row_shr:4
    x = dpp_add<0x118, 0xf, true >(x);   // row_shr:8
    x = dpp_add<0x142, 0xa, false>(x);   // row_bcast:15 -> rows 1,3
    x = dpp_add<0x143, 0xc, false>(x);   // row_bcast:31 -> rows 2,3
    return x;
}

// One wave per (gram, a, b) pair, compact grid:
//   blocks [0,2080)      gram 0 = K(X_a,X_b), a<=b (upper triangle)
//   blocks [2080,4160)   gram 1 = K(Y_a,Y_b), a<=b
//   blocks [4160,8256)   gram 2 = K(X_a,Y_b), all pairs
//
// Left-aligned Goursat rows: lane l holds KL = K[p][64s+l]. Per row p:
//   m[l]      = (s[p+1]-s[p]) * KL        (s[p] = dot(U_row[p], dV_row[q]), lane-local)
//   KL_new[l] = (Kb_new - Kb_old) + KL[l] + (incl_scan(m)[l] - m[l])
// where Kb = K[.][64s] strip-base boundary. Strip 0: Kb==1; column-64 value
// tracked as uniform bK (bK += readlane(scan,63)) and stored to bnd[] for
// strip 1, which reads Kb_old/Kb_new from bnd[]. No per-row shuffles at all.
__global__ __launch_bounds__(64, 4) void sig_goursat_kernel(
        const float* __restrict__ X, const float* __restrict__ Y,
        float* __restrict__ Kout)
{
    const int bid = blockIdx.x;
    int g, a, b;
    if (bid < 4160) {                  // symmetric grams, triangular index
        g = bid < 2080 ? 0 : 1;
        const int t = bid - g * 2080;
        // row offsets: off(a) = a*(129-a)/2; invert with sqrt + integer fix
        float sq = sqrtf(4160.25f - 2.0f * (float)t);
        a = (int)(64.5f - sq);
        if (a < 0) a = 0; if (a > 63) a = 63;
        while (a > 0  && (a * (129 - a)) / 2 > t) --a;
        while (a < 63 && ((a + 1) * (128 - a)) / 2 <= t) ++a;
        b = a + (t - (a * (129 - a)) / 2);
    } else {
        const int t = bid - 4160;
        g = 2; a = t >> 6; b = t & 63;
    }

    const float* __restrict__ U = (g == 1 ? Y : X) + (size_t)a * (MM * DD);
    const float* __restrict__ V = (g == 0 ? X : Y) + (size_t)b * (MM * DD);

    const int lane = threadIdx.x;
    __shared__ float bnd[MM + 1];      // bnd[p] = K[p][64]

    float result = 0.0f;

    for (int s = 0; s < 2; ++s) {
        const int q  = s * 64 + lane;
        const int qa = q > 126 ? 126 : q;     // clamp (s=1, lane=63: no cell; harmless)
        const float* __restrict__ Vr0 = V + (size_t)qa * DD;
        const float* __restrict__ Vr1 = Vr0 + DD;

        // ---- dV row in 16 named float4 regs, PINNED so it can't be remat'd ----
#define DVDECL(i) float4 dv##i;
        FOR16(DVDECL)
#define DVLOAD(i) { float4 v0_ = *(const float4*)(Vr0 + 4*(i)); \
                    float4 v1_ = *(const float4*)(Vr1 + 4*(i)); \
                    dv##i.x = v1_.x - v0_.x; dv##i.y = v1_.y - v0_.y; \
                    dv##i.z = v1_.z - v0_.z; dv##i.w = v1_.w - v0_.w; }
        FOR16(DVLOAD)
#define DVPIN(i) asm volatile("" : "+v"(dv##i.x), "+v"(dv##i.y), \
                                   "+v"(dv##i.z), "+v"(dv##i.w));
        FOR16(DVPIN)

#define DOTSTEP(i) { float4 u_ = *(const float4*)(ur_ + 4*(i)); \
                     acc0 = fmaf(u_.x, dv##i.x, acc0); \
                     acc1 = fmaf(u_.y, dv##i.y, acc1); \
                     acc2 = fmaf(u_.z, dv##i.z, acc2); \
                     acc3 = fmaf(u_.w, dv##i.w, acc3); }
#define DOT(rowptr, out) { const float* __restrict__ ur_ = (rowptr); \
                           float acc0 = 0.f, acc1 = 0.f, acc2 = 0.f, acc3 = 0.f; \
                           FOR16(DOTSTEP) \
                           out = (acc0 + acc1) + (acc2 + acc3); }

        float KL    = 1.0f;    // K[0][q] = 1
        float bK    = 1.0f;    // strip 0: running K[p][64]
        float prevB = 1.0f;    // strip 1: bnd[p]
        float s0;
        DOT(U, s0)

        for (int p = 0; p < PP; ++p) {
            float curB = 0.0f;
            if (s == 1) curB = bnd[p + 1];        // uniform LDS read, issued early
            float s1;
            DOT(U + (size_t)(p + 1) * DD, s1)
            const float m = (s1 - s0) * KL;
            s0 = s1;
            const float sc = wave_incl_scan(m);   // inclusive scan of m
            if (s == 0) {
                KL += sc - m;                     // Kb_new == Kb_old == 1
                bK += __int_as_float(__builtin_amdgcn_readlane(__float_as_int(sc), 63));
                if (lane == 0) bnd[p + 1] = bK;   // K[p+1][64] for strip 1
            } else {
                KL += (curB - prevB) + (sc - m);
                prevB = curB;
            }
        }
        if (s == 1 && lane == 63) result = KL;    // K[127][127]
    }

    if (lane == 63) Kout[(size_t)g * 4096 + a * 64 + b] = result;
}

// Deterministic weighted reduction + the mean((X0-Y0)^2) term.
__global__ void sig_reduce_kernel(const float* __restrict__ X,
                                  const float* __restrict__ Y,
                                  const float* __restrict__ Kws,
                                  float* __restrict__ out)
{
    const int t = threadIdx.x;
    double accK = 0.0, acc2 = 0.0;
    for (int i = t; i < 4096; i += 256) {
        const int a = i >> 6, b = i & 63;
        if (a <= b) {
            const double w = (a == b) ? 1.0 : 2.0;
            accK += w * (double)Kws[i];           // XX
            accK += w * (double)Kws[4096 + i];    // YY
        }
        accK -= 2.0 * (double)Kws[8192 + i];      // XY
        // mean((X[:,0,:] - Y[:,0,:])^2): element (a, d=b)
        const float df = X[(size_t)a * (MM * DD) + b] - Y[(size_t)a * (MM * DD) + b];
        acc2 += (double)df * (double)df;
    }
    __shared__ double red[256];
    red[t] = accK / 4096.0 + acc2 / 4096.0;
    __syncthreads();
    for (int s = 128; s > 0; s >>= 1) {
        if (t < s) red[t] += red[t + s];
        __syncthreads();
    }
    if (t == 0) out[0] = (float)red[0];
}

extern "C" void kernel_launch(void* const* d_in, const int* in_sizes, int n_in,
                              void* d_out, int out_size, void* d_ws, size_t ws_size,
                              hipStream_t stream) {
    const float* X = (const float*)d_in[0];
    const float* Y = (const float*)d_in[1];
    float* Kws = (float*)d_ws;          // 3 * 4096 floats
    float* out = (float*)d_out;

    sig_goursat_kernel<<<dim3(8256), dim3(64), 0, stream>>>(X, Y, Kws);
    sig_reduce_kernel<<<dim3(1), dim3(256), 0, stream>>>(X, Y, Kws, out);
}